// Round 5
// baseline (366.188 us; speedup 1.0000x reference)
//
#include <hip/hip_runtime.h>
#include <hip/hip_bf16.h>
#include <cstdint>

// Problem constants (match reference)
#define B_ 256
#define N_ 131072
#define D_ 256
#define INV_TEMP 20.0f   // 1/0.05
#define EPS_SM 1e-6f
#define EPS_LOG 1e-6f

// GEMM tiling: 512 blocks (2/CU), each owns 256 cf rows. Chunk = 64 rows x 64 K.
#define TPB 512            // 8 waves; wave w owns A rows w*32..w*32+31
#define BROWS 256          // cf rows per block
#define BN 64              // cf rows per chunk
#define BK 64              // K elems per chunk
#define NCHUNK 16          // (BROWS/BN=4 groups) * (D_/BK=4 kc)
#define CHUNK_B 16384      // 64 rows * 64 cols * 4B (fp32 staged)
#define NBUF 4             // 4 x 16KB = 64KB; buffer = c & 3; prefetch depth 2
#define A_OFF 28672        // A-phase region [28672, 65536): disjoint from buf0
#define LDB 72             // A-phase ushort row stride (64+8 pad)
#define NSLOT 32
#define NBLK (N_ / BROWS)  // 512 blocks -> 2 per CU (64KB LDS each)

typedef __bf16 bf16_t;
typedef bf16_t bf16x8 __attribute__((ext_vector_type(8)));
typedef float f32x4 __attribute__((ext_vector_type(4)));

struct alignas(16) U8 { ushort u[8]; };

// Native f32->bf16 RNE (v_cvt_pk_bf16_f32) — same rounding as original bit-twiddle.
__device__ inline ushort f2bf(float f) { return __builtin_bit_cast(ushort, (__bf16)f); }

__device__ inline void cvt_store8(ushort* dst, const float4 a, const float4 b) {
  U8 w;
  w.u[0] = f2bf(a.x); w.u[1] = f2bf(a.y); w.u[2] = f2bf(a.z); w.u[3] = f2bf(a.w);
  w.u[4] = f2bf(b.x); w.u[5] = f2bf(b.y); w.u[6] = f2bf(b.z); w.u[7] = f2bf(b.w);
  *(uint4*)dst = __builtin_bit_cast(uint4, w);
}

// Read 8 fp32 from LDS (32B, swizzle-aligned) -> bf16x8 fragment.
__device__ inline bf16x8 cvt_frag(const char* p) {
  const float4 v0 = *(const float4*)p;
  const float4 v1 = *(const float4*)(p + 16);
  U8 w;
  w.u[0] = f2bf(v0.x); w.u[1] = f2bf(v0.y); w.u[2] = f2bf(v0.z); w.u[3] = f2bf(v0.w);
  w.u[4] = f2bf(v1.x); w.u[5] = f2bf(v1.y); w.u[6] = f2bf(v1.z); w.u[7] = f2bf(v1.w);
  return __builtin_bit_cast(bf16x8, w);
}

// LDS-only barrier: orders ds ops, does NOT drain vmcnt (in-flight DMA survives).
__device__ inline void bar_ds() {
  asm volatile("s_waitcnt lgkmcnt(0)" ::: "memory");
  __builtin_amdgcn_s_barrier();
}

// Direct global->LDS DMA, 16B per lane. Dest is wave-uniform-base + lane*16
// (hardware semantics); we pass the per-lane pointer whose lane-0 value is the base.
__device__ inline void load_lds16(const float* g, char* l) {
  __builtin_amdgcn_global_load_lds(
      (const __attribute__((address_space(1))) void*)g,
      (__attribute__((address_space(3))) void*)l, 16, 0, 0);
}

// VGPR: areg 64 (MFMA-A, AGPR-eligible) + acc 32 (AGPR) + small temps — no
// register-held prefetch state (the round-4 spill source is gone).
__global__ __launch_bounds__(TPB, 4)
void gemm_rowsum_fused(const float* __restrict__ inp, const float* __restrict__ cf,
                       const int* __restrict__ idx, const int* __restrict__ lab,
                       float* __restrict__ rowsum, unsigned* __restrict__ counter,
                       float* __restrict__ out) {
  __shared__ float4 smem4[4096];  // 64 KB: bufs 0..3 at [0,64K); A-phase at [28672,64K)
  __shared__ unsigned done;
  char* smem = (char*)smem4;
  const int tid  = threadIdx.x;
  const int wave = tid >> 6;
  const int lane = tid & 63;
  const int m15  = lane & 15;
  const int q    = lane >> 4;

  const size_t nbase = (size_t)blockIdx.x * BROWS;

  // ---- Staging geometry (per thread, chunk-invariant).
  // LDS linear byte L = i*8192 + tid*16 (i=0,1) -> row = L>>8, colbyte = L&255.
  // Swizzle: LDS(row, cb) holds global col-byte cb ^ ((row&7)<<5)  [32B granular].
  const int srow = tid >> 4;                               // row for issue 0 (0..31)
  const int ssw  = (((tid & 15) * 16) ^ ((srow & 7) << 5)) >> 2;  // src col (floats); same for i=1 (row+32)
#define STAGE(c) do {                                                                  \
    const float* g0 = cf + (nbase + (size_t)(((c) >> 2) * BN + srow)) * D_             \
                         + ((c) & 3) * BK + ssw;                                       \
    char* l0 = smem + ((c) & 3) * CHUNK_B + tid * 16;                                  \
    load_lds16(g0, l0);                                                                \
    load_lds16(g0 + 32 * D_, l0 + 8192);                                               \
  } while (0)

  // ---- Start the HBM stream immediately: chunk 0 DMA (buf0 disjoint from A region).
  STAGE(0);

  // ---- A phase: inp -> bf16 LDS (top region) -> MFMA fragments. bar_ds only
  // (lgkm): the chunk-0 DMA stays in flight across these barriers.
  ushort* asu = (ushort*)(smem + A_OFF);
  bf16x8 areg[8][2];
#pragma unroll
  for (int kc = 0; kc < 4; ++kc) {
    const int row = tid >> 1, half = tid & 1;
    const float* src = inp + row * D_ + kc * BK + half * 32;
#pragma unroll
    for (int j = 0; j < 4; ++j) {
      const float4 v0 = *(const float4*)(src + j * 8);
      const float4 v1 = *(const float4*)(src + j * 8 + 4);
      cvt_store8(&asu[row * LDB + half * 32 + j * 8], v0, v1);
    }
    bar_ds();
#pragma unroll
    for (int mb = 0; mb < 2; ++mb)
#pragma unroll
      for (int ks = 0; ks < 2; ++ks)
        areg[kc * 2 + ks][mb] = __builtin_bit_cast(
            bf16x8, *(const uint4*)(&asu[(wave * 32 + mb * 16 + m15) * LDB + ks * 32 + q * 8]));
    bar_ds();  // all A reads drained block-wide before chunk1+ DMA may overwrite region
  }

  STAGE(1);  // now safe: buf1 overlapped the A region

  f32x4 acc[2][4];
  float rs[2][4];
#pragma unroll
  for (int mb = 0; mb < 2; ++mb) {
#pragma unroll
    for (int nb = 0; nb < 4; ++nb) acc[mb][nb] = (f32x4){0.f, 0.f, 0.f, 0.f};
#pragma unroll
    for (int r = 0; r < 4; ++r) rs[mb][r] = 0.f;
  }

  // Per-lane swizzled read col-bytes (frag row = nb*16+m15, so row&7 = m15&7).
  const int sA = (m15 & 7) << 5;
  const int t0 = (q * 32) ^ sA;          // ks=0 col-byte
  const int t1 = (128 + q * 32) ^ sA;    // ks=1 col-byte

  // ---- Steady state: 16 chunks, DMA depth 2, counted vmcnt (never 0 mid-loop).
  // Iter c: issue stage(c+2); wait vmcnt(4) => chunk c's 2 loads landed (per wave);
  // barrier => all 8 waves' slices landed; compute from buf[c&3].
  // Buffer safety: stage(c+2) targets buf[(c+2)&3], last read at iter c-2, whose
  // ds_reads drained at iter c-1's barrier (lgkmcnt(0) precedes every barrier).
#pragma unroll
  for (int c = 0; c < NCHUNK; ++c) {
    if (c + 2 < NCHUNK) STAGE(c + 2);
    if (c < NCHUNK - 2) {
      asm volatile("s_waitcnt vmcnt(4) lgkmcnt(0)" ::: "memory");
    } else if (c == NCHUNK - 2) {
      asm volatile("s_waitcnt vmcnt(2) lgkmcnt(0)" ::: "memory");
    } else {
      asm volatile("s_waitcnt vmcnt(0) lgkmcnt(0)" ::: "memory");
    }
    __builtin_amdgcn_s_barrier();
    __builtin_amdgcn_sched_barrier(0);

    const char* bs = smem + (c & 3) * CHUNK_B;
#pragma unroll
    for (int ks = 0; ks < 2; ++ks) {
      bf16x8 bfr[4];
#pragma unroll
      for (int nb = 0; nb < 4; ++nb)
        bfr[nb] = cvt_frag(bs + (nb * 16 + m15) * 256 + (ks ? t1 : t0));
#pragma unroll
      for (int mb = 0; mb < 2; ++mb)
#pragma unroll
        for (int nb = 0; nb < 4; ++nb)
          acc[mb][nb] = __builtin_amdgcn_mfma_f32_16x16x32_bf16(
              areg[(c & 3) * 2 + ks][mb], bfr[nb], acc[mb][nb], 0, 0, 0);
    }
    if ((c & 3) == 3) {  // group finished (full K): fold exp into row-sums
#pragma unroll
      for (int mb = 0; mb < 2; ++mb)
#pragma unroll
        for (int nb = 0; nb < 4; ++nb)
#pragma unroll
          for (int r = 0; r < 4; ++r)
            rs[mb][r] += __expf(acc[mb][nb][r] * INV_TEMP);
      if (c + 1 < NCHUNK) {
#pragma unroll
        for (int mb = 0; mb < 2; ++mb)
#pragma unroll
          for (int nb = 0; nb < 4; ++nb) acc[mb][nb] = (f32x4){0.f, 0.f, 0.f, 0.f};
      }
    }
  }
#undef STAGE

  // C/D layout: col = lane&15 (folded), row = wave*32 + mb*16 + q*4 + r.
#pragma unroll
  for (int off = 8; off >= 1; off >>= 1)
#pragma unroll
    for (int mb = 0; mb < 2; ++mb)
#pragma unroll
      for (int r = 0; r < 4; ++r)
        rs[mb][r] += __shfl_xor(rs[mb][r], off, 64);

  if (m15 == 0) {
    float* slot = rowsum + (blockIdx.x & (NSLOT - 1)) * B_;
#pragma unroll
    for (int mb = 0; mb < 2; ++mb)
#pragma unroll
      for (int r = 0; r < 4; ++r)
        atomicAdd(&slot[wave * 32 + mb * 16 + q * 4 + r], rs[mb][r]);
  }

  // ---- Fused finalize: last block to finish computes the loss.
  __syncthreads();  // full sync: drains this block's atomics
  if (tid == 0) {
    __threadfence();
    const unsigned prev = __hip_atomic_fetch_add(counter, 1u, __ATOMIC_ACQ_REL,
                                                 __HIP_MEMORY_SCOPE_AGENT);
    done = (prev == (unsigned)(NBLK - 1)) ? 1u : 0u;
  }
  __syncthreads();
  if (done) {
    __threadfence();
    float* red = (float*)smem;  // [0,512) dot partials, [512,768) log terms
    const int b = tid >> 1, part = tid & 1;
    const int t = lab[idx[b]];
    const float4* a4 = (const float4*)(inp + b * D_ + part * 128);
    const float4* c4 = (const float4*)(cf + (size_t)t * D_ + part * 128);
    float dot = 0.f;
#pragma unroll
    for (int i = 0; i < 32; ++i) {
      const float4 x = a4[i], y = c4[i];
      dot += x.x * y.x + x.y * y.y + x.z * y.z + x.w * y.w;
    }
    red[tid] = dot;
    __syncthreads();
    if (tid < 256) {
      const float d = red[2 * tid] + red[2 * tid + 1];
      float S = 0.f;
#pragma unroll
      for (int s = 0; s < NSLOT; ++s)
        S += __hip_atomic_load(&rowsum[s * B_ + tid], __ATOMIC_RELAXED,
                               __HIP_MEMORY_SCOPE_AGENT);
      red[512 + tid] = __logf(__expf(d * INV_TEMP) / (S + EPS_SM) + EPS_LOG);
    }
    __syncthreads();
    for (int off = 128; off >= 1; off >>= 1) {
      if (tid < off) red[512 + tid] += red[512 + tid + off];
      __syncthreads();
    }
    if (tid == 0) out[0] = -red[512] * (1.0f / 256.0f);
  }
}

extern "C" void kernel_launch(void* const* d_in, const int* in_sizes, int n_in,
                              void* d_out, int out_size, void* d_ws, size_t ws_size,
                              hipStream_t stream) {
  const float* inp = (const float*)d_in[0];  // inputs [256,256]
  const float* cf  = (const float*)d_in[1];  // cluster_features [131072,256]
  // d_in[2] = instance_features: unused by the reference
  const int* idx = (const int*)d_in[3];      // indexes [256]
  const int* lab = (const int*)d_in[4];      // labels [131072]
  float* out = (float*)d_out;
  float* rowsum = (float*)d_ws;              // NSLOT * 256 floats
  unsigned* counter = (unsigned*)(rowsum + NSLOT * B_);

  hipMemsetAsync(d_ws, 0, (NSLOT * B_ + 16) * sizeof(float), stream);
  gemm_rowsum_fused<<<dim3(NBLK), dim3(TPB), 0, stream>>>(inp, cf, idx, lab,
                                                          rowsum, counter, out);
}